// Round 10
// baseline (105303.284 us; speedup 1.0000x reference)
//
#include <hip/hip_runtime.h>
#include <math.h>
#include <stdint.h>

#define SEQ   4096
#define NWG   256
#define NTHR  256
#define FINTAG 0x40000000u

// ws layout in dwords. Cells are 8B {f32 h, u32 tag}.
#define WS_BIG  0                    // big ring  [4][1536] cells
#define WS_SML  12288                // small ring [4][768] cells
#define WS_FIN  18432                // final cells [256]
#define WS_OUTP 18944                // outp [4096][256] f32
#define WS_ZERO WS_OUTP

typedef float f32x4 __attribute__((ext_vector_type(4)));
typedef float f32x2 __attribute__((ext_vector_type(2)));

// fast, saturation-safe activations (v_exp_f32 / v_rcp_f32) — validated R9
__device__ __forceinline__ float sigf(float x){
  float e = __builtin_amdgcn_exp2f(-1.44269504089f * x);   // exp(-x)
  return __builtin_amdgcn_rcpf(1.0f + e);
}
__device__ __forceinline__ float tanhf_fast(float x){
  float e = __builtin_amdgcn_exp2f(2.88539008178f * x);    // exp(2x)
  return 1.0f - 2.0f * __builtin_amdgcn_rcpf(e + 1.0f);    // +-inf-safe
}

__device__ __forceinline__ float wsum64(float v){
#pragma unroll
  for (int m = 32; m > 0; m >>= 1) v += __shfl_xor(v, m);
  return v;
}

__device__ __forceinline__ float g_load(const float* p){
  return __hip_atomic_load(p, __ATOMIC_RELAXED, __HIP_MEMORY_SCOPE_AGENT);
}
__device__ __forceinline__ void g_store(float* p, float v){
  __hip_atomic_store(p, v, __ATOMIC_RELAXED, __HIP_MEMORY_SCOPE_AGENT);
}
// single 8B atomic store: {h, tag} — data IS the signal (bypasses L2 -> LLC)
__device__ __forceinline__ void cell_store(float* cell, float h, unsigned tag){
  unsigned long long pk = ((unsigned long long)tag << 32) | (unsigned long long)__float_as_uint(h);
  __hip_atomic_store((unsigned long long*)cell, pk, __ATOMIC_RELAXED, __HIP_MEMORY_SCOPE_AGENT);
}

#define DOT4(acc, wv4, hv4) \
  acc += (wv4)[0]*(hv4)[0] + (wv4)[1]*(hv4)[1] + (wv4)[2]*(hv4)[2] + (wv4)[3]*(hv4)[3];

// Cache-relay retry: CACHED loads (L1/L2 allowed). On stale tag: acquire-agent
// fence (buffer_inv: L1+L2 invalidate) then reload — first reloader per XCD
// pulls fresh lines into its L2; the other ~31 WGs then hit L2, not LLC.
// Ring lines are never dirty in L2 (producers store sc1, consumers never
// write), so invalidate-without-writeback is safe.
#define RETRY_FULL(bbp, sbp, sb2p, tgv)                                      \
  for(;;){                                                                   \
    asm volatile(                                                            \
      "global_load_dwordx4 %0, %5, off\n\t"                                  \
      "global_load_dwordx4 %1, %5, off offset:1024\n\t"                      \
      "global_load_dwordx4 %2, %5, off offset:2048\n\t"                      \
      "global_load_dwordx4 %3, %6, off\n\t"                                  \
      "global_load_dwordx2 %4, %7, off\n\t"                                  \
      "s_waitcnt vmcnt(0)"                                                   \
      : "=&v"(B0), "=&v"(B1), "=&v"(B2), "=&v"(S0), "=&v"(S1v)               \
      : "v"(bbp), "v"(sbp), "v"(sb2p) : "memory");                           \
    unsigned tgu = (unsigned)(tgv);                                          \
    bool ok = (__float_as_uint(B0[1])==tgu) & (__float_as_uint(B0[3])==tgu)  \
            & (__float_as_uint(B1[1])==tgu) & (__float_as_uint(B1[3])==tgu)  \
            & (__float_as_uint(B2[1])==tgu) & (__float_as_uint(B2[3])==tgu)  \
            & (__float_as_uint(S0[1])==tgu) & (__float_as_uint(S0[3])==tgu)  \
            & (__float_as_uint(S1v[1])==tgu);                                \
    if (__all(ok)) break;                                                    \
    __builtin_amdgcn_fence(__ATOMIC_ACQUIRE, "agent");                       \
    __builtin_amdgcn_s_sleep(1);                                             \
  }

#define RETRY_SMALL(sbp, sb2p, tgv)                                          \
  for(;;){                                                                   \
    asm volatile(                                                            \
      "global_load_dwordx4 %0, %2, off\n\t"                                  \
      "global_load_dwordx2 %1, %3, off\n\t"                                  \
      "s_waitcnt vmcnt(0)"                                                   \
      : "=&v"(S0), "=&v"(S1v)                                                \
      : "v"(sbp), "v"(sb2p) : "memory");                                     \
    unsigned tgu = (unsigned)(tgv);                                          \
    bool ok = (__float_as_uint(S0[1])==tgu) & (__float_as_uint(S0[3])==tgu)  \
            & (__float_as_uint(S1v[1])==tgu);                                \
    if (__all(ok)) break;                                                    \
    __builtin_amdgcn_fence(__ATOMIC_ACQUIRE, "agent");                       \
    __builtin_amdgcn_s_sleep(1);                                             \
  }

__global__ void init_ws(float* ws){
  int i = threadIdx.x + blockIdx.x*blockDim.x;
  for (; i < WS_ZERO; i += blockDim.x*gridDim.x)
    __hip_atomic_store(ws + i, 0.0f, __ATOMIC_RELAXED, __HIP_MEMORY_SCOPE_AGENT);
}

__global__ __launch_bounds__(NTHR, 1) void lstm_ae(
    const float* __restrict__ x,
    const float* __restrict__ e1Wih, const float* __restrict__ e1Whh,
    const float* __restrict__ e1bih, const float* __restrict__ e1bhh,
    const float* __restrict__ e2Wih, const float* __restrict__ e2Whh,
    const float* __restrict__ e2bih, const float* __restrict__ e2bhh,
    const float* __restrict__ d1Wih, const float* __restrict__ d1Whh,
    const float* __restrict__ d1bih, const float* __restrict__ d1bhh,
    const float* __restrict__ d2Wih, const float* __restrict__ d2Whh,
    const float* __restrict__ d2bih, const float* __restrict__ d2bhh,
    const float* __restrict__ outW, const float* __restrict__ outb,
    float* __restrict__ out, float* __restrict__ ws)
{
  const int w    = blockIdx.x;
  const int tid  = threadIdx.x;
  const int lane = tid & 63;
  const int v    = tid >> 6;          // wave 0..3 == gate index

  float* outp = ws + WS_OUTP;

  __shared__ float lx[SEQ];           // 16 KB input
  __shared__ float lhB[2][1536];      // staged big h, double-buffered
  __shared__ float lhS[2][768];       // staged small h, double-buffered
  __shared__ float lgB[24], lgS[12];  // gate pre-activations [gate][unit]

  for (int i = tid; i < SEQ; i += NTHR) lx[i] = x[i];

  // ---- weights: gate-parallel mapping. wave v owns gate v of all units. ----
  // big rows: v*1536 + 6w + r (r=0..5). small rows: v*768 + 3w + r (r=0..2).
  // frag (q,j) multiplies h[256q + 4*lane + j].
  f32x4 wR[6][6];   // e1Whh -> d2Whh      (K=1536)
  f32x4 wA[18];     // e2Wih r*6+q (r<3) -> d2Wih r*3+q (r<6)
  f32x4 wB[9];      // e2Whh r*3+q -> d1Wih (Z) -> d1Whh (D)
  float wihB[6], biasB[6], biasS[3], zw[3], bz[3];

#pragma unroll
  for (int r = 0; r < 6; ++r){
    const int row = v*1536 + 6*w + r;
    const float* p = e1Whh + (size_t)row*1536 + 4*lane;
#pragma unroll
    for (int q = 0; q < 6; ++q) wR[r][q] = *(const f32x4*)(p + 256*q);
    wihB[r]  = e1Wih[row];
    biasB[r] = e1bih[row] + e1bhh[row];
  }
#pragma unroll
  for (int r = 0; r < 3; ++r){
    const int row = v*768 + 3*w + r;
    const float* pi = e2Wih + (size_t)row*1536 + 4*lane;
#pragma unroll
    for (int q = 0; q < 6; ++q) wA[r*6+q] = *(const f32x4*)(pi + 256*q);
    const float* ph = e2Whh + (size_t)row*768 + 4*lane;
#pragma unroll
    for (int q = 0; q < 3; ++q) wB[r*3+q] = *(const f32x4*)(ph + 256*q);
    biasS[r] = e2bih[row] + e2bhh[row];
  }

  float cB = 0.0f, cS = 0.0f;   // wave0 lanes 0-5: big cell state; lanes 8-10: small
  const float ob = outb[0];
  float ow = (v == 0 && lane < 6) ? outW[6*w + lane] : 0.0f;

  __syncthreads();   // lx staged

  // ================= Phase EN: iter g consumes packet g, produces g+1 =================
  for (int g = 0; g <= SEQ; ++g){
    const int slot = g & 3, buf = g & 1;
    {
      const float* bigb = ws + WS_BIG + slot*3072;
      const float* smlb = ws + WS_SML + slot*1536;
      const float* bb  = bigb + (384*v + 2*lane)*2;
      const float* sb  = smlb + (192*v + 2*lane)*2;
      const float* sb2 = smlb + (192*v + 128 + lane)*2;
      f32x4 B0,B1,B2,S0; f32x2 S1v;
      RETRY_FULL(bb, sb, sb2, g);
      *(f32x2*)&lhB[buf][384*v +       2*lane] = f32x2{B0[0], B0[2]};
      *(f32x2*)&lhB[buf][384*v + 128 + 2*lane] = f32x2{B1[0], B1[2]};
      *(f32x2*)&lhB[buf][384*v + 256 + 2*lane] = f32x2{B2[0], B2[2]};
      *(f32x2*)&lhS[buf][192*v +       2*lane] = f32x2{S0[0], S0[2]};
      lhS[buf][192*v + 128 + lane] = S1v[0];
    }
    __syncthreads();                   // S1

    f32x4 H[6], S[3];
#pragma unroll
    for (int q = 0; q < 6; ++q) H[q] = *(const f32x4*)&lhB[buf][256*q + 4*lane];
#pragma unroll
    for (int q = 0; q < 3; ++q) S[q] = *(const f32x4*)&lhS[buf][256*q + 4*lane];

    float a0=0.f,a1=0.f,a2=0.f,a3=0.f,a4=0.f,a5=0.f;
    if (g < SEQ){      // e1: gate v of units 0..5
#pragma unroll
      for (int q = 0; q < 6; ++q){
        DOT4(a0, wR[0][q], H[q]); DOT4(a1, wR[1][q], H[q]); DOT4(a2, wR[2][q], H[q]);
        DOT4(a3, wR[3][q], H[q]); DOT4(a4, wR[4][q], H[q]); DOT4(a5, wR[5][q], H[q]);
      }
      a0=wsum64(a0); a1=wsum64(a1); a2=wsum64(a2);
      a3=wsum64(a3); a4=wsum64(a4); a5=wsum64(a5);
    }
    float b0=0.f,b1=0.f,b2=0.f;
    if (g >= 1){       // e2: gate v of units 0..2
#pragma unroll
      for (int q = 0; q < 6; ++q){
        DOT4(b0, wA[0*6+q], H[q]); DOT4(b1, wA[1*6+q], H[q]); DOT4(b2, wA[2*6+q], H[q]);
      }
#pragma unroll
      for (int q = 0; q < 3; ++q){
        DOT4(b0, wB[0*3+q], S[q]); DOT4(b1, wB[1*3+q], S[q]); DOT4(b2, wB[2*3+q], S[q]);
      }
      b0=wsum64(b0); b1=wsum64(b1); b2=wsum64(b2);
    }
    if (lane == 0){
      if (g < SEQ){
        float xt = lx[g];
        lgB[v*6+0]=a0+wihB[0]*xt+biasB[0]; lgB[v*6+1]=a1+wihB[1]*xt+biasB[1];
        lgB[v*6+2]=a2+wihB[2]*xt+biasB[2]; lgB[v*6+3]=a3+wihB[3]*xt+biasB[3];
        lgB[v*6+4]=a4+wihB[4]*xt+biasB[4]; lgB[v*6+5]=a5+wihB[5]*xt+biasB[5];
      }
      if (g >= 1){
        lgS[v*3+0]=b0+biasS[0]; lgS[v*3+1]=b1+biasS[1]; lgS[v*3+2]=b2+biasS[2];
      }
    }
    __syncthreads();                   // S2

    if (v == 0){       // produce packet g+1 (each cell: one 8B store, no flags)
      float* nbig = ws + WS_BIG + ((g+1)&3)*3072;
      float* nsml = ws + WS_SML + ((g+1)&3)*1536;
      if (g < SEQ && lane < 6){
        float gi=lgB[lane],gf=lgB[6+lane],gg=lgB[12+lane],go=lgB[18+lane];
        cB = sigf(gf)*cB + sigf(gi)*tanhf_fast(gg);
        cell_store(nbig + (6*w+lane)*2, sigf(go)*tanhf_fast(cB), (unsigned)(g+1));
      }
      if (lane >= 8 && lane < 11){
        int u = lane - 8;
        float hv = 0.0f;
        if (g >= 1){
          float gi=lgS[u],gf=lgS[3+u],gg=lgS[6+u],go=lgS[9+u];
          cS = sigf(gf)*cS + sigf(gi)*tanhf_fast(gg);
          hv = sigf(go)*tanhf_fast(cS);
        }
        cell_store(nsml + (3*w+u)*2, hv, (unsigned)(g+1));  // g==0: zero state for packet 1
      }
    }
  }

  // ================= Phase Z: zW = d1_Wih @ z + bias (consumes packet SEQ+1 small) =================
  {
#pragma unroll
    for (int r = 0; r < 3; ++r){
      const int row = v*768 + 3*w + r;
      const float* p = d1Wih + (size_t)row*768 + 4*lane;
#pragma unroll
      for (int q = 0; q < 3; ++q) wB[r*3+q] = *(const f32x4*)(p + 256*q);
      bz[r] = d1bih[row] + d1bhh[row];
    }
    const int tg = SEQ+1, slot = tg & 3, buf = tg & 1;
    const float* smlb = ws + WS_SML + slot*1536;
    const float* sb  = smlb + (192*v + 2*lane)*2;
    const float* sb2 = smlb + (192*v + 128 + lane)*2;
    f32x4 S0; f32x2 S1v;
    RETRY_SMALL(sb, sb2, tg);
    *(f32x2*)&lhS[buf][192*v + 2*lane] = f32x2{S0[0], S0[2]};
    lhS[buf][192*v + 128 + lane] = S1v[0];
    __syncthreads();
    f32x4 S[3];
#pragma unroll
    for (int q = 0; q < 3; ++q) S[q] = *(const f32x4*)&lhS[buf][256*q + 4*lane];
    float z0=0.f,z1=0.f,z2=0.f;
#pragma unroll
    for (int q = 0; q < 3; ++q){
      DOT4(z0, wB[0*3+q], S[q]); DOT4(z1, wB[1*3+q], S[q]); DOT4(z2, wB[2*3+q], S[q]);
    }
    zw[0]=wsum64(z0)+bz[0]; zw[1]=wsum64(z1)+bz[1]; zw[2]=wsum64(z2)+bz[2];
  }

  // ---- D-phase weights ----
#pragma unroll
  for (int r = 0; r < 6; ++r){
    const int row = v*1536 + 6*w + r;
    const float* p = d2Whh + (size_t)row*1536 + 4*lane;
#pragma unroll
    for (int q = 0; q < 6; ++q) wR[r][q] = *(const f32x4*)(p + 256*q);
    const float* pi = d2Wih + (size_t)row*768 + 4*lane;
#pragma unroll
    for (int q = 0; q < 3; ++q) wA[r*3+q] = *(const f32x4*)(pi + 256*q);
    biasB[r] = d2bih[row] + d2bhh[row];
  }
#pragma unroll
  for (int r = 0; r < 3; ++r){
    const int row = v*768 + 3*w + r;
    const float* p = d1Whh + (size_t)row*768 + 4*lane;
#pragma unroll
    for (int q = 0; q < 3; ++q) wB[r*3+q] = *(const f32x4*)(p + 256*q);
  }
  cB = 0.0f; cS = 0.0f;

  // ================= Phase D: iter t consumes packet SEQ+1+t, produces +1 =================
  for (int t = 0; t <= SEQ; ++t){
    const int pc = SEQ+1+t, slot = pc & 3, buf = pc & 1;
    if (t >= 1){
      const float* bigb = ws + WS_BIG + slot*3072;
      const float* smlb = ws + WS_SML + slot*1536;
      const float* bb  = bigb + (384*v + 2*lane)*2;
      const float* sb  = smlb + (192*v + 2*lane)*2;
      const float* sb2 = smlb + (192*v + 128 + lane)*2;
      f32x4 B0,B1,B2,S0; f32x2 S1v;
      RETRY_FULL(bb, sb, sb2, pc);
      *(f32x2*)&lhB[buf][384*v +       2*lane] = f32x2{B0[0], B0[2]};
      *(f32x2*)&lhB[buf][384*v + 128 + 2*lane] = f32x2{B1[0], B1[2]};
      *(f32x2*)&lhB[buf][384*v + 256 + 2*lane] = f32x2{B2[0], B2[2]};
      *(f32x2*)&lhS[buf][192*v +       2*lane] = f32x2{S0[0], S0[2]};
      lhS[buf][192*v + 128 + lane] = S1v[0];
    }
    __syncthreads();                   // S1

    f32x4 H[6], S[3];
    if (t >= 1){
#pragma unroll
      for (int q = 0; q < 6; ++q) H[q] = *(const f32x4*)&lhB[buf][256*q + 4*lane];
#pragma unroll
      for (int q = 0; q < 3; ++q) S[q] = *(const f32x4*)&lhS[buf][256*q + 4*lane];
    } else {
#pragma unroll
      for (int q = 0; q < 6; ++q) H[q] = (f32x4)0.0f;
#pragma unroll
      for (int q = 0; q < 3; ++q) S[q] = (f32x4)0.0f;
    }

    float b0=0.f,b1=0.f,b2=0.f;
    if (t < SEQ){      // d1: gate v of units 0..2
#pragma unroll
      for (int q = 0; q < 3; ++q){
        DOT4(b0, wB[0*3+q], S[q]); DOT4(b1, wB[1*3+q], S[q]); DOT4(b2, wB[2*3+q], S[q]);
      }
      b0=wsum64(b0); b1=wsum64(b1); b2=wsum64(b2);
    }
    float a0=0.f,a1=0.f,a2=0.f,a3=0.f,a4=0.f,a5=0.f;
    if (t >= 1){       // d2: big recurrent (H) + small input (S)
#pragma unroll
      for (int q = 0; q < 6; ++q){
        DOT4(a0, wR[0][q], H[q]); DOT4(a1, wR[1][q], H[q]); DOT4(a2, wR[2][q], H[q]);
        DOT4(a3, wR[3][q], H[q]); DOT4(a4, wR[4][q], H[q]); DOT4(a5, wR[5][q], H[q]);
      }
#pragma unroll
      for (int q = 0; q < 3; ++q){
        DOT4(a0, wA[0*3+q], S[q]); DOT4(a1, wA[1*3+q], S[q]); DOT4(a2, wA[2*3+q], S[q]);
        DOT4(a3, wA[3*3+q], S[q]); DOT4(a4, wA[4*3+q], S[q]); DOT4(a5, wA[5*3+q], S[q]);
      }
      a0=wsum64(a0); a1=wsum64(a1); a2=wsum64(a2);
      a3=wsum64(a3); a4=wsum64(a4); a5=wsum64(a5);
    }
    if (lane == 0){
      if (t < SEQ){
        lgS[v*3+0]=b0+zw[0]; lgS[v*3+1]=b1+zw[1]; lgS[v*3+2]=b2+zw[2];
      }
      if (t >= 1){
        lgB[v*6+0]=a0+biasB[0]; lgB[v*6+1]=a1+biasB[1]; lgB[v*6+2]=a2+biasB[2];
        lgB[v*6+3]=a3+biasB[3]; lgB[v*6+4]=a4+biasB[4]; lgB[v*6+5]=a5+biasB[5];
      }
    }
    __syncthreads();                   // S2

    if (v == 0){       // produce packet pc+1
      float* nbig = ws + WS_BIG + ((pc+1)&3)*3072;
      float* nsml = ws + WS_SML + ((pc+1)&3)*1536;
      if (t < SEQ && lane >= 8 && lane < 11){
        int u = lane - 8;
        float gi=lgS[u],gf=lgS[3+u],gg=lgS[6+u],go=lgS[9+u];
        cS = sigf(gf)*cS + sigf(gi)*tanhf_fast(gg);
        cell_store(nsml + (3*w+u)*2, sigf(go)*tanhf_fast(cS), (unsigned)(pc+1));
      }
      float vv = 0.0f;
      if (lane < 6){
        float hv = 0.0f;
        if (t >= 1){
          float gi=lgB[lane],gf=lgB[6+lane],gg=lgB[12+lane],go=lgB[18+lane];
          cB = sigf(gf)*cB + sigf(gi)*tanhf_fast(gg);
          hv = sigf(go)*tanhf_fast(cB);
          vv = hv * ow;
        }
        cell_store(nbig + (6*w+lane)*2, hv, (unsigned)(pc+1));  // t==0: hd2 zero state
      }
      if (t >= 1 && lane < 8){
        vv += __shfl_xor(vv,1); vv += __shfl_xor(vv,2); vv += __shfl_xor(vv,4);
        if (lane == 0) g_store(&outp[(size_t)(t-1)*NWG + w], vv);
      }
    }
  }

  // ================= Finalize + reduce =================
  if (v == 0){
    asm volatile("s_waitcnt vmcnt(0)" ::: "memory");   // all outp/cell stores acked
    if (lane == 0) cell_store(ws + WS_FIN + w*2, 0.0f, FINTAG);
    const float* fb = ws + WS_FIN + (4*lane)*2;
    f32x4 F0, F1;
    for(;;){
      asm volatile(
        "global_load_dwordx4 %0, %2, off\n\t"
        "global_load_dwordx4 %1, %2, off offset:16\n\t"
        "s_waitcnt vmcnt(0)"
        : "=&v"(F0), "=&v"(F1) : "v"(fb) : "memory");
      bool ok = (__float_as_uint(F0[1])==FINTAG)&(__float_as_uint(F0[3])==FINTAG)
              & (__float_as_uint(F1[1])==FINTAG)&(__float_as_uint(F1[3])==FINTAG);
      if (__all(ok)) break;
      __builtin_amdgcn_fence(__ATOMIC_ACQUIRE, "agent");
      __builtin_amdgcn_s_sleep(1);
    }
  }
  __syncthreads();
  {
    const int tau = w*16 + (tid >> 4);
    const int s4  = tid & 15;
    float s = 0.f;
#pragma unroll
    for (int j = 0; j < 16; ++j) s += g_load(&outp[(size_t)tau*NWG + s4 + 16*j]);
    s += __shfl_xor(s,8); s += __shfl_xor(s,4); s += __shfl_xor(s,2); s += __shfl_xor(s,1);
    if (s4 == 0) out[tau] = s + ob;
  }
}

extern "C" void kernel_launch(void* const* d_in, const int* in_sizes, int n_in,
                              void* d_out, int out_size, void* d_ws, size_t ws_size,
                              hipStream_t stream){
  (void)in_sizes; (void)n_in; (void)out_size; (void)ws_size;
  const float* x     = (const float*)d_in[0];
  const float* e1Wih = (const float*)d_in[1];
  const float* e1Whh = (const float*)d_in[2];
  const float* e1bih = (const float*)d_in[3];
  const float* e1bhh = (const float*)d_in[4];
  const float* e2Wih = (const float*)d_in[5];
  const float* e2Whh = (const float*)d_in[6];
  const float* e2bih = (const float*)d_in[7];
  const float* e2bhh = (const float*)d_in[8];
  const float* d1Wih = (const float*)d_in[9];
  const float* d1Whh = (const float*)d_in[10];
  const float* d1bih = (const float*)d_in[11];
  const float* d1bhh = (const float*)d_in[12];
  const float* d2Wih = (const float*)d_in[13];
  const float* d2Whh = (const float*)d_in[14];
  const float* d2bih = (const float*)d_in[15];
  const float* d2bhh = (const float*)d_in[16];
  const float* outW  = (const float*)d_in[17];
  const float* outb  = (const float*)d_in[18];
  float* out = (float*)d_out;
  float* ws  = (float*)d_ws;

  hipLaunchKernelGGL(init_ws, dim3(32), dim3(256), 0, stream, ws);

  // Plain launch (NOT cooperative): co-residency follows from grid == #CUs
  // at 1 block/CU (high-VGPR kernel); cooperative launch rejects this config.
  hipLaunchKernelGGL(lstm_ae, dim3(NWG), dim3(NTHR), 0, stream,
                     x,
                     e1Wih, e1Whh, e1bih, e1bhh,
                     e2Wih, e2Whh, e2bih, e2bhh,
                     d1Wih, d1Whh, d1bih, d1bhh,
                     d2Wih, d2Whh, d2bih, d2bhh,
                     outW,  outb,  out,   ws);
}

// Round 12
// 24922.478 us; speedup vs baseline: 4.2252x; 4.2252x over previous
//
#include <hip/hip_runtime.h>
#include <math.h>
#include <stdint.h>

#define SEQ   4096
#define NWG   256
#define NTHR  256
#define FINTAG 0x40000000u

// ws layout in dwords. Cells are 8B {f32 h, u32 tag}.
#define WS_BIG  0                    // big ring  [4][1536] cells
#define WS_SML  12288                // small ring [4][768] cells
#define WS_FIN  18432                // final cells [256]
#define WS_OUTP 18944                // outp [4096][256] f32
#define WS_ZERO WS_OUTP

typedef float f32x4 __attribute__((ext_vector_type(4)));
typedef float f32x2 __attribute__((ext_vector_type(2)));

// fast, saturation-safe activations (v_exp_f32 / v_rcp_f32) — validated R9 (absmax 0.0)
__device__ __forceinline__ float sigf(float x){
  float e = __builtin_amdgcn_exp2f(-1.44269504089f * x);   // exp(-x)
  return __builtin_amdgcn_rcpf(1.0f + e);
}
__device__ __forceinline__ float tanhf_fast(float x){
  float e = __builtin_amdgcn_exp2f(2.88539008178f * x);    // exp(2x)
  return 1.0f - 2.0f * __builtin_amdgcn_rcpf(e + 1.0f);    // +-inf-safe
}

__device__ __forceinline__ float wsum64(float v){
#pragma unroll
  for (int m = 32; m > 0; m >>= 1) v += __shfl_xor(v, m);
  return v;
}

__device__ __forceinline__ float g_load(const float* p){
  return __hip_atomic_load(p, __ATOMIC_RELAXED, __HIP_MEMORY_SCOPE_AGENT);
}
__device__ __forceinline__ void g_store(float* p, float v){
  __hip_atomic_store(p, v, __ATOMIC_RELAXED, __HIP_MEMORY_SCOPE_AGENT);
}
// single 8B atomic store: {h, tag} — data IS the signal (sc1 -> LLC)
__device__ __forceinline__ void cell_store(float* cell, float h, unsigned tag){
  unsigned long long pk = ((unsigned long long)tag << 32) | (unsigned long long)__float_as_uint(h);
  __hip_atomic_store((unsigned long long*)cell, pk, __ATOMIC_RELAXED, __HIP_MEMORY_SCOPE_AGENT);
}

#define DOT4(acc, wv4, hv4) \
  acc += (wv4)[0]*(hv4)[0] + (wv4)[1]*(hv4)[1] + (wv4)[2]*(hv4)[2] + (wv4)[3]*(hv4)[3];

// R8-proven transport: sc1 (LLC-direct) loads of this wave's DISJOINT slice.
#define RETRY_BIG(bbp, tgv)                                                  \
  for(;;){                                                                   \
    asm volatile(                                                            \
      "global_load_dwordx4 %0, %3, off sc0 sc1\n\t"                          \
      "global_load_dwordx4 %1, %3, off offset:1024 sc0 sc1\n\t"              \
      "global_load_dwordx4 %2, %3, off offset:2048 sc0 sc1\n\t"              \
      "s_waitcnt vmcnt(0)"                                                   \
      : "=&v"(B0), "=&v"(B1), "=&v"(B2)                                      \
      : "v"(bbp) : "memory");                                                \
    unsigned tgu = (unsigned)(tgv);                                          \
    bool ok = (__float_as_uint(B0[1])==tgu) & (__float_as_uint(B0[3])==tgu)  \
            & (__float_as_uint(B1[1])==tgu) & (__float_as_uint(B1[3])==tgu)  \
            & (__float_as_uint(B2[1])==tgu) & (__float_as_uint(B2[3])==tgu); \
    if (__all(ok)) break;                                                    \
    __builtin_amdgcn_s_sleep(1);                                             \
  }

#define RETRY_SML(sbp, sb2p, tgv)                                            \
  for(;;){                                                                   \
    asm volatile(                                                            \
      "global_load_dwordx4 %0, %2, off sc0 sc1\n\t"                          \
      "global_load_dwordx2 %1, %3, off sc0 sc1\n\t"                          \
      "s_waitcnt vmcnt(0)"                                                   \
      : "=&v"(S0), "=&v"(S1v)                                                \
      : "v"(sbp), "v"(sb2p) : "memory");                                     \
    unsigned tgu = (unsigned)(tgv);                                          \
    bool ok = (__float_as_uint(S0[1])==tgu) & (__float_as_uint(S0[3])==tgu)  \
            & (__float_as_uint(S1v[1])==tgu);                                \
    if (__all(ok)) break;                                                    \
    __builtin_amdgcn_s_sleep(1);                                             \
  }

__global__ void init_ws(float* ws){
  int i = threadIdx.x + blockIdx.x*blockDim.x;
  for (; i < WS_ZERO; i += blockDim.x*gridDim.x)
    __hip_atomic_store(ws + i, 0.0f, __ATOMIC_RELAXED, __HIP_MEMORY_SCOPE_AGENT);
}

__global__ __launch_bounds__(NTHR, 1) void lstm_ae(
    const float* __restrict__ x,
    const float* __restrict__ e1Wih, const float* __restrict__ e1Whh,
    const float* __restrict__ e1bih, const float* __restrict__ e1bhh,
    const float* __restrict__ e2Wih, const float* __restrict__ e2Whh,
    const float* __restrict__ e2bih, const float* __restrict__ e2bhh,
    const float* __restrict__ d1Wih, const float* __restrict__ d1Whh,
    const float* __restrict__ d1bih, const float* __restrict__ d1bhh,
    const float* __restrict__ d2Wih, const float* __restrict__ d2Whh,
    const float* __restrict__ d2bih, const float* __restrict__ d2bhh,
    const float* __restrict__ outW, const float* __restrict__ outb,
    float* __restrict__ out, float* __restrict__ ws)
{
  const int w    = blockIdx.x;
  const int tid  = threadIdx.x;
  const int lane = tid & 63;
  const int v    = tid >> 6;          // wave 0..3 == gate index

  float* outp = ws + WS_OUTP;

  __shared__ float lx[SEQ];           // 16 KB input
  __shared__ float lhB[2][1536];      // staged big h, double-buffered
  __shared__ float lhS[2][768];       // staged small h, double-buffered
  __shared__ float lgB[24], lgS[12];  // gate pre-activations [gate][unit]

  for (int i = tid; i < SEQ; i += NTHR) lx[i] = x[i];

  // ---- weights: gate-parallel mapping. wave v owns gate v of all units. ----
  // big rows: v*1536 + 6w + r (r=0..5). small rows: v*768 + 3w + r (r=0..2).
  // frag (q,j) multiplies h[256q + 4*lane + j].
  f32x4 wR[6][6];   // e1Whh -> d2Whh      (K=1536)
  f32x4 wA[18];     // e2Wih r*6+q (r<3) -> d2Wih r*3+q (r<6)
  f32x4 wB[9];      // e2Whh r*3+q -> d1Wih (Z) -> d1Whh (D)
  float wihB[6], biasB[6], biasS[3], zw[3], bz[3];

#pragma unroll
  for (int r = 0; r < 6; ++r){
    const int row = v*1536 + 6*w + r;
    const float* p = e1Whh + (size_t)row*1536 + 4*lane;
#pragma unroll
    for (int q = 0; q < 6; ++q) wR[r][q] = *(const f32x4*)(p + 256*q);
    wihB[r]  = e1Wih[row];
    biasB[r] = e1bih[row] + e1bhh[row];
  }
#pragma unroll
  for (int r = 0; r < 3; ++r){
    const int row = v*768 + 3*w + r;
    const float* pi = e2Wih + (size_t)row*1536 + 4*lane;
#pragma unroll
    for (int q = 0; q < 6; ++q) wA[r*6+q] = *(const f32x4*)(pi + 256*q);
    const float* ph = e2Whh + (size_t)row*768 + 4*lane;
#pragma unroll
    for (int q = 0; q < 3; ++q) wB[r*3+q] = *(const f32x4*)(ph + 256*q);
    biasS[r] = e2bih[row] + e2bhh[row];
  }

  float cB = 0.0f, cS = 0.0f;   // wave0 lanes 0-5: big cell state; lanes 8-10: small
  const float ob = outb[0];
  float ow = (v == 0 && lane < 6) ? outW[6*w + lane] : 0.0f;

  __syncthreads();   // lx staged

  // ========== Phase EN: critical = e1 big chain; e2 deferred ==========
  // packet g: big = h1[g] (tag g), small = h2[g-1] (tag g)
  for (int g = 0; g <= SEQ; ++g){
    const int slot = g & 3, buf = g & 1;
    {  // --- early: catch big h1[g] ---
      const float* bb = ws + WS_BIG + slot*3072 + (384*v + 2*lane)*2;
      f32x4 B0,B1,B2;
      RETRY_BIG(bb, g);
      *(f32x2*)&lhB[buf][384*v +       2*lane] = f32x2{B0[0], B0[2]};
      *(f32x2*)&lhB[buf][384*v + 128 + 2*lane] = f32x2{B1[0], B1[2]};
      *(f32x2*)&lhB[buf][384*v + 256 + 2*lane] = f32x2{B2[0], B2[2]};
    }
    __syncthreads();                   // S1: big staged

    if (g < SEQ){                      // e1: gate v of units 0..5
      f32x4 H[6];
#pragma unroll
      for (int q = 0; q < 6; ++q) H[q] = *(const f32x4*)&lhB[buf][256*q + 4*lane];
      float a0=0.f,a1=0.f,a2=0.f,a3=0.f,a4=0.f,a5=0.f;
#pragma unroll
      for (int q = 0; q < 6; ++q){
        DOT4(a0, wR[0][q], H[q]); DOT4(a1, wR[1][q], H[q]); DOT4(a2, wR[2][q], H[q]);
        DOT4(a3, wR[3][q], H[q]); DOT4(a4, wR[4][q], H[q]); DOT4(a5, wR[5][q], H[q]);
      }
      a0=wsum64(a0); a1=wsum64(a1); a2=wsum64(a2);
      a3=wsum64(a3); a4=wsum64(a4); a5=wsum64(a5);
      if (lane == 0){
        float xt = lx[g];
        lgB[v*6+0]=a0+wihB[0]*xt+biasB[0]; lgB[v*6+1]=a1+wihB[1]*xt+biasB[1];
        lgB[v*6+2]=a2+wihB[2]*xt+biasB[2]; lgB[v*6+3]=a3+wihB[3]*xt+biasB[3];
        lgB[v*6+4]=a4+wihB[4]*xt+biasB[4]; lgB[v*6+5]=a5+wihB[5]*xt+biasB[5];
      }
    }
    __syncthreads();                   // S2: lgB ready

    if (v == 0 && g < SEQ && lane < 6){  // store h1[g+1] ASAP — recurrence-critical
      float gi=lgB[lane],gf=lgB[6+lane],gg=lgB[12+lane],go=lgB[18+lane];
      cB = sigf(gf)*cB + sigf(gi)*tanhf_fast(gg);
      cell_store(ws + WS_BIG + ((g+1)&3)*3072 + (6*w+lane)*2,
                 sigf(go)*tanhf_fast(cB), (unsigned)(g+1));
    }

    // --- deferred: catch small h2[g-1], compute e2, store h2[g] ---
    if (g >= 1){
      const float* smlb = ws + WS_SML + slot*1536;
      const float* sb  = smlb + (192*v + 2*lane)*2;
      const float* sb2 = smlb + (192*v + 128 + lane)*2;
      f32x4 S0; f32x2 S1v;
      RETRY_SML(sb, sb2, g);
      *(f32x2*)&lhS[buf][192*v + 2*lane] = f32x2{S0[0], S0[2]};
      lhS[buf][192*v + 128 + lane] = S1v[0];
    }
    __syncthreads();                   // S3: small staged

    if (g >= 1){                       // e2: gate v of units 0..2
      f32x4 H[6], S[3];
#pragma unroll
      for (int q = 0; q < 6; ++q) H[q] = *(const f32x4*)&lhB[buf][256*q + 4*lane];
#pragma unroll
      for (int q = 0; q < 3; ++q) S[q] = *(const f32x4*)&lhS[buf][256*q + 4*lane];
      float b0=0.f,b1=0.f,b2=0.f;
#pragma unroll
      for (int q = 0; q < 6; ++q){
        DOT4(b0, wA[0*6+q], H[q]); DOT4(b1, wA[1*6+q], H[q]); DOT4(b2, wA[2*6+q], H[q]);
      }
#pragma unroll
      for (int q = 0; q < 3; ++q){
        DOT4(b0, wB[0*3+q], S[q]); DOT4(b1, wB[1*3+q], S[q]); DOT4(b2, wB[2*3+q], S[q]);
      }
      b0=wsum64(b0); b1=wsum64(b1); b2=wsum64(b2);
      if (lane == 0){
        lgS[v*3+0]=b0+biasS[0]; lgS[v*3+1]=b1+biasS[1]; lgS[v*3+2]=b2+biasS[2];
      }
    }
    __syncthreads();                   // S4: lgS ready

    // Store small tag g+1 UNCONDITIONALLY: at g==0 it is the zero initial
    // state h2[0] — omitting it deadlocks the g==1 consumers (R11 bug).
    if (v == 0 && lane >= 8 && lane < 11){
      int u = lane - 8;
      float hv = 0.0f;
      if (g >= 1){
        float gi=lgS[u],gf=lgS[3+u],gg=lgS[6+u],go=lgS[9+u];
        cS = sigf(gf)*cS + sigf(gi)*tanhf_fast(gg);
        hv = sigf(go)*tanhf_fast(cS);
      }
      cell_store(ws + WS_SML + ((g+1)&3)*1536 + (3*w+u)*2, hv, (unsigned)(g+1));
    }
  }

  // ========== Phase Z: zW = d1_Wih @ z + bias (packet SEQ+1 small = z) ==========
  {
#pragma unroll
    for (int r = 0; r < 3; ++r){
      const int row = v*768 + 3*w + r;
      const float* p = d1Wih + (size_t)row*768 + 4*lane;
#pragma unroll
      for (int q = 0; q < 3; ++q) wB[r*3+q] = *(const f32x4*)(p + 256*q);
      bz[r] = d1bih[row] + d1bhh[row];
    }
    const int tg = SEQ+1, slot = tg & 3, buf = tg & 1;
    const float* smlb = ws + WS_SML + slot*1536;
    const float* sb  = smlb + (192*v + 2*lane)*2;
    const float* sb2 = smlb + (192*v + 128 + lane)*2;
    f32x4 S0; f32x2 S1v;
    RETRY_SML(sb, sb2, tg);
    *(f32x2*)&lhS[buf][192*v + 2*lane] = f32x2{S0[0], S0[2]};
    lhS[buf][192*v + 128 + lane] = S1v[0];
    __syncthreads();
    f32x4 S[3];
#pragma unroll
    for (int q = 0; q < 3; ++q) S[q] = *(const f32x4*)&lhS[buf][256*q + 4*lane];
    float z0=0.f,z1=0.f,z2=0.f;
#pragma unroll
    for (int q = 0; q < 3; ++q){
      DOT4(z0, wB[0*3+q], S[q]); DOT4(z1, wB[1*3+q], S[q]); DOT4(z2, wB[2*3+q], S[q]);
    }
    zw[0]=wsum64(z0)+bz[0]; zw[1]=wsum64(z1)+bz[1]; zw[2]=wsum64(z2)+bz[2];
  }

  // ---- D-phase weights ----
#pragma unroll
  for (int r = 0; r < 6; ++r){
    const int row = v*1536 + 6*w + r;
    const float* p = d2Whh + (size_t)row*1536 + 4*lane;
#pragma unroll
    for (int q = 0; q < 6; ++q) wR[r][q] = *(const f32x4*)(p + 256*q);
    const float* pi = d2Wih + (size_t)row*768 + 4*lane;
#pragma unroll
    for (int q = 0; q < 3; ++q) wA[r*3+q] = *(const f32x4*)(pi + 256*q);
    biasB[r] = d2bih[row] + d2bhh[row];
  }
#pragma unroll
  for (int r = 0; r < 3; ++r){
    const int row = v*768 + 3*w + r;
    const float* p = d1Whh + (size_t)row*768 + 4*lane;
#pragma unroll
    for (int q = 0; q < 3; ++q) wB[r*3+q] = *(const f32x4*)(p + 256*q);
  }
  cB = 0.0f; cS = 0.0f;

  // ========== Phase D: critical = d1 small chain; d2 deferred ==========
  // packet pc=SEQ+1+t: small = hd1[t], big = hd2[t-1]
  for (int t = 0; t <= SEQ; ++t){
    const int pc = SEQ+1+t, slot = pc & 3, buf = pc & 1;
    if (t >= 1){  // --- early: catch small hd1[t] ---
      const float* smlb = ws + WS_SML + slot*1536;
      const float* sb  = smlb + (192*v + 2*lane)*2;
      const float* sb2 = smlb + (192*v + 128 + lane)*2;
      f32x4 S0; f32x2 S1v;
      RETRY_SML(sb, sb2, pc);
      *(f32x2*)&lhS[buf][192*v + 2*lane] = f32x2{S0[0], S0[2]};
      lhS[buf][192*v + 128 + lane] = S1v[0];
    }
    __syncthreads();                   // S1: small staged

    if (t < SEQ){                      // d1: gate v of units 0..2
      f32x4 S[3];
      if (t >= 1){
#pragma unroll
        for (int q = 0; q < 3; ++q) S[q] = *(const f32x4*)&lhS[buf][256*q + 4*lane];
      } else {
#pragma unroll
        for (int q = 0; q < 3; ++q) S[q] = (f32x4)0.0f;
      }
      float b0=0.f,b1=0.f,b2=0.f;
#pragma unroll
      for (int q = 0; q < 3; ++q){
        DOT4(b0, wB[0*3+q], S[q]); DOT4(b1, wB[1*3+q], S[q]); DOT4(b2, wB[2*3+q], S[q]);
      }
      b0=wsum64(b0); b1=wsum64(b1); b2=wsum64(b2);
      if (lane == 0){
        lgS[v*3+0]=b0+zw[0]; lgS[v*3+1]=b1+zw[1]; lgS[v*3+2]=b2+zw[2];
      }
    }
    __syncthreads();                   // S2: lgS ready

    if (v == 0){                       // store hd1[t+1] ASAP — recurrence-critical
      if (t < SEQ && lane >= 8 && lane < 11){
        int u = lane - 8;
        float gi=lgS[u],gf=lgS[3+u],gg=lgS[6+u],go=lgS[9+u];
        cS = sigf(gf)*cS + sigf(gi)*tanhf_fast(gg);
        cell_store(ws + WS_SML + ((pc+1)&3)*1536 + (3*w+u)*2,
                   sigf(go)*tanhf_fast(cS), (unsigned)(pc+1));
      }
      if (t == 0 && lane < 6)          // hd2[0] = 0 (slot holds stale data)
        cell_store(ws + WS_BIG + ((pc+1)&3)*3072 + (6*w+lane)*2, 0.0f, (unsigned)(pc+1));
    }

    // --- deferred: catch big hd2[t-1], compute d2, store hd2[t] + out partial ---
    if (t >= 1){
      const float* bb = ws + WS_BIG + slot*3072 + (384*v + 2*lane)*2;
      f32x4 B0,B1,B2;
      RETRY_BIG(bb, pc);
      *(f32x2*)&lhB[buf][384*v +       2*lane] = f32x2{B0[0], B0[2]};
      *(f32x2*)&lhB[buf][384*v + 128 + 2*lane] = f32x2{B1[0], B1[2]};
      *(f32x2*)&lhB[buf][384*v + 256 + 2*lane] = f32x2{B2[0], B2[2]};
    }
    __syncthreads();                   // S3: big staged

    if (t >= 1){                       // d2: gate v of units 0..5
      f32x4 H[6], S[3];
#pragma unroll
      for (int q = 0; q < 6; ++q) H[q] = *(const f32x4*)&lhB[buf][256*q + 4*lane];
#pragma unroll
      for (int q = 0; q < 3; ++q) S[q] = *(const f32x4*)&lhS[buf][256*q + 4*lane];
      float a0=0.f,a1=0.f,a2=0.f,a3=0.f,a4=0.f,a5=0.f;
#pragma unroll
      for (int q = 0; q < 6; ++q){
        DOT4(a0, wR[0][q], H[q]); DOT4(a1, wR[1][q], H[q]); DOT4(a2, wR[2][q], H[q]);
        DOT4(a3, wR[3][q], H[q]); DOT4(a4, wR[4][q], H[q]); DOT4(a5, wR[5][q], H[q]);
      }
#pragma unroll
      for (int q = 0; q < 3; ++q){
        DOT4(a0, wA[0*3+q], S[q]); DOT4(a1, wA[1*3+q], S[q]); DOT4(a2, wA[2*3+q], S[q]);
        DOT4(a3, wA[3*3+q], S[q]); DOT4(a4, wA[4*3+q], S[q]); DOT4(a5, wA[5*3+q], S[q]);
      }
      a0=wsum64(a0); a1=wsum64(a1); a2=wsum64(a2);
      a3=wsum64(a3); a4=wsum64(a4); a5=wsum64(a5);
      if (lane == 0){
        lgB[v*6+0]=a0+biasB[0]; lgB[v*6+1]=a1+biasB[1]; lgB[v*6+2]=a2+biasB[2];
        lgB[v*6+3]=a3+biasB[3]; lgB[v*6+4]=a4+biasB[4]; lgB[v*6+5]=a5+biasB[5];
      }
    }
    __syncthreads();                   // S4: lgB ready

    if (v == 0 && t >= 1){
      float vv = 0.0f;
      if (lane < 6){
        float gi=lgB[lane],gf=lgB[6+lane],gg=lgB[12+lane],go=lgB[18+lane];
        cB = sigf(gf)*cB + sigf(gi)*tanhf_fast(gg);
        float hv = sigf(go)*tanhf_fast(cB);
        cell_store(ws + WS_BIG + ((pc+1)&3)*3072 + (6*w+lane)*2, hv, (unsigned)(pc+1));
        vv = hv * ow;
      }
      if (lane < 8){
        vv += __shfl_xor(vv,1); vv += __shfl_xor(vv,2); vv += __shfl_xor(vv,4);
        if (lane == 0) g_store(&outp[(size_t)(t-1)*NWG + w], vv);
      }
    }
  }

  // ================= Finalize + reduce =================
  if (v == 0){
    asm volatile("s_waitcnt vmcnt(0)" ::: "memory");   // all outp/cell stores acked
    if (lane == 0) cell_store(ws + WS_FIN + w*2, 0.0f, FINTAG);
    const float* fb = ws + WS_FIN + (4*lane)*2;
    f32x4 F0, F1;
    for(;;){
      asm volatile(
        "global_load_dwordx4 %0, %2, off sc0 sc1\n\t"
        "global_load_dwordx4 %1, %2, off offset:16 sc0 sc1\n\t"
        "s_waitcnt vmcnt(0)"
        : "=&v"(F0), "=&v"(F1) : "v"(fb) : "memory");
      bool ok = (__float_as_uint(F0[1])==FINTAG)&(__float_as_uint(F0[3])==FINTAG)
              & (__float_as_uint(F1[1])==FINTAG)&(__float_as_uint(F1[3])==FINTAG);
      if (__all(ok)) break;
      __builtin_amdgcn_s_sleep(1);
    }
  }
  __syncthreads();
  {
    const int tau = w*16 + (tid >> 4);
    const int s4  = tid & 15;
    float s = 0.f;
#pragma unroll
    for (int j = 0; j < 16; ++j) s += g_load(&outp[(size_t)tau*NWG + s4 + 16*j]);
    s += __shfl_xor(s,8); s += __shfl_xor(s,4); s += __shfl_xor(s,2); s += __shfl_xor(s,1);
    if (s4 == 0) out[tau] = s + ob;
  }
}

extern "C" void kernel_launch(void* const* d_in, const int* in_sizes, int n_in,
                              void* d_out, int out_size, void* d_ws, size_t ws_size,
                              hipStream_t stream){
  (void)in_sizes; (void)n_in; (void)out_size; (void)ws_size;
  const float* x     = (const float*)d_in[0];
  const float* e1Wih = (const float*)d_in[1];
  const float* e1Whh = (const float*)d_in[2];
  const float* e1bih = (const float*)d_in[3];
  const float* e1bhh = (const float*)d_in[4];
  const float* e2Wih = (const float*)d_in[5];
  const float* e2Whh = (const float*)d_in[6];
  const float* e2bih = (const float*)d_in[7];
  const float* e2bhh = (const float*)d_in[8];
  const float* d1Wih = (const float*)d_in[9];
  const float* d1Whh = (const float*)d_in[10];
  const float* d1bih = (const float*)d_in[11];
  const float* d1bhh = (const float*)d_in[12];
  const float* d2Wih = (const float*)d_in[13];
  const float* d2Whh = (const float*)d_in[14];
  const float* d2bih = (const float*)d_in[15];
  const float* d2bhh = (const float*)d_in[16];
  const float* outW  = (const float*)d_in[17];
  const float* outb  = (const float*)d_in[18];
  float* out = (float*)d_out;
  float* ws  = (float*)d_ws;

  hipLaunchKernelGGL(init_ws, dim3(32), dim3(256), 0, stream, ws);

  // Plain launch (NOT cooperative): co-residency follows from grid == #CUs
  // at 1 block/CU (high-VGPR kernel); cooperative launch rejects this config.
  hipLaunchKernelGGL(lstm_ae, dim3(NWG), dim3(NTHR), 0, stream,
                     x,
                     e1Wih, e1Whh, e1bih, e1bhh,
                     e2Wih, e2Whh, e2bih, e2bhh,
                     d1Wih, d1Whh, d1bih, d1bhh,
                     d2Wih, d2Whh, d2bih, d2bhh,
                     outW,  outb,  out,   ws);
}